// Round 2
// baseline (83.762 us; speedup 1.0000x reference)
//
#include <hip/hip_runtime.h>
#include <hip/hip_bf16.h>

namespace {

constexpr int B_N = 8;
constexpr int A_N = 100000;
constexpr int C_N = 8;
constexpr int M_N = 128;
constexpr int BLOCK = 256;
constexpr int APT = 2;                            // anchors per thread
constexpr int TILE = BLOCK * APT;                 // 512
constexpr int NBLK = (A_N + TILE - 1) / TILE;     // 196

// ---------------------------------------------------------------------------
// Main kernel: 2 anchors per thread. grid = (NBLK, B).
// Inner loop is the hot path: ~17 VALU/anchor/box, no branches, no divides.
// ---------------------------------------------------------------------------
__global__ __launch_bounds__(BLOCK) void focal_main(
    const float* __restrict__ cls_,      // (B, A, C)
    const float* __restrict__ reg_,      // (B, A, 8)
    const float* __restrict__ anchors_,  // (1, A, 4)
    const float* __restrict__ ann_,      // (B, M, 18)
    float* __restrict__ partials)        // (B, NBLK, 4)
{
    __shared__ float4 s_bb[M_N];    // box2d (x1,y1,x2,y2); invalid -> (inf,inf,-inf,-inf)
    __shared__ float  s_area[M_N];  // box2d area; invalid -> 0

    const int b   = blockIdx.y;
    const int tid = threadIdx.x;
    const float* annb = ann_ + (size_t)b * M_N * 18;

    // Stage box2d. Validity folded into coordinates so the hot loop has no
    // validity test: inter=0 and (bn>=0 init) => update condition never fires.
    if (tid < M_N) {
        const float* t = annb + tid * 18;
        float minx = t[0], maxx = t[0], miny = t[1], maxy = t[1];
#pragma unroll
        for (int j = 1; j < 8; ++j) {
            const float xj = t[2 * j], yj = t[2 * j + 1];
            minx = fminf(minx, xj); maxx = fmaxf(maxx, xj);
            miny = fminf(miny, yj); maxy = fmaxf(maxy, yj);
        }
        float area = (maxx - minx) * (maxy - miny);
        if (t[17] < 0.0f) {  // invalid annotation
            minx = INFINITY; miny = INFINITY; maxx = -INFINITY; maxy = -INFINITY;
            area = 0.0f;
        }
        s_bb[tid]   = make_float4(minx, miny, maxx, maxy);
        s_area[tid] = area;
    }
    __syncthreads();

    const int base = blockIdx.x * TILE;
    const int a0 = base + tid;
    const int a1 = base + BLOCK + tid;
    const int c0 = min(a0, A_N - 1);   // clamped for safe loads on tail block
    const int c1 = min(a1, A_N - 1);

    const float4 an0 = ((const float4*)anchors_)[c0];
    const float4 an1 = ((const float4*)anchors_)[c1];
    const float aarea0 = (an0.z - an0.x) * (an0.w - an0.y);
    const float aarea1 = (an1.z - an1.x) * (an1.w - an1.y);

    // Division-free running argmax of IoU = bn/bd. Init (0,1): correct pos/neg
    // classification always; kbest correct whenever iou_max>0 (all pos anchors).
    // ua clamp dropped: ua >= max(aarea,barea) > 0 for every reachable case.
    float bn0 = 0.f, bd0 = 1.f, bn1 = 0.f, bd1 = 1.f;
    int   kb0 = 0,   kb1 = 0;

#pragma unroll 4
    for (int m = 0; m < M_N; ++m) {
        const float4 bb = s_bb[m];     // uniform-address broadcast reads
        const float  ba = s_area[m];

        const float iw0 = fminf(an0.z, bb.z) - fmaxf(an0.x, bb.x);
        const float ih0 = fminf(an0.w, bb.w) - fmaxf(an0.y, bb.y);
        const float in0 = fmaxf(iw0, 0.f) * fmaxf(ih0, 0.f);
        const float ua0 = (aarea0 + ba) - in0;
        const bool  u0  = in0 * bd0 > bn0 * ua0;
        bn0 = u0 ? in0 : bn0;
        bd0 = u0 ? ua0 : bd0;
        kb0 = u0 ? m   : kb0;

        const float iw1 = fminf(an1.z, bb.z) - fmaxf(an1.x, bb.x);
        const float ih1 = fminf(an1.w, bb.w) - fmaxf(an1.y, bb.y);
        const float in1 = fmaxf(iw1, 0.f) * fmaxf(ih1, 0.f);
        const float ua1 = (aarea1 + ba) - in1;
        const bool  u1  = in1 * bd1 > bn1 * ua1;
        bn1 = u1 ? in1 : bn1;
        bd1 = u1 ? ua1 : bd1;
        kb1 = u1 ? m   : kb1;
    }

    float clsS = 0.f, regS = 0.f, vpS = 0.f, posC = 0.f;

    auto epilogue = [&](int a, const float4& an, float bn, float bd, int kb) {
        if (a >= A_N) return;
        const bool pos = (bn + bn) >= bd;        // iou >= 0.5
        const bool neg = (5.0f * bn) < (bd + bd); // iou < 0.4

        // ---- classification focal loss --------------------------------
        const float* cp = cls_ + ((size_t)b * A_N + a) * C_N;
        const float4 cA = ((const float4*)cp)[0];
        const float4 cB = ((const float4*)cp)[1];
        const float pv[8] = {cA.x, cA.y, cA.z, cA.w, cB.x, cB.y, cB.z, cB.w};

        float tt[16];
        int   kc = -1;
        if (pos) {  // rare: read assigned annotation straight from global
            const float* t = annb + kb * 18;
#pragma unroll
            for (int j = 0; j < 16; ++j) tt[j] = t[j];
            kc = (int)t[17];
        }

        float sneg = 0.f, pkc = 0.5f, negkc = 0.f;
#pragma unroll
        for (int c = 0; c < C_N; ++c) {
            const float pc   = fminf(fmaxf(pv[c], 1e-4f), 1.0f - 1e-4f);
            const float term = 0.75f * pc * pc * (-__logf(1.0f - pc));
            sneg += term;
            if (c == kc) { pkc = pc; negkc = term; }  // static unrolled selects
        }
        if (pos | neg)
            clsS += pos ? (sneg - negkc +
                           0.25f * (1.0f - pkc) * (1.0f - pkc) * (-__logf(pkc)))
                        : sneg;

        // ---- regression + vp (pos anchors only) -----------------------
        if (pos) {
            posC += 1.0f;
            const float aw  = an.z - an.x;
            const float ah  = an.w - an.y;
            const float acx = an.x + 0.5f * aw;
            const float acy = an.y + 0.5f * ah;

            const float* rp = reg_ + ((size_t)b * A_N + a) * 8;
            const float4 r0 = ((const float4*)rp)[0];
            const float4 r1 = ((const float4*)rp)[1];

            auto vp = [](float rx, float ry, float tx, float ty) {
                const float denom = sqrtf(rx * rx + ry * ry) * sqrtf(tx * tx + ty * ty);
                return 1.0f - (rx * tx + ry * ty) / fmaxf(denom, 1e-8f);
            };
            const float vp1 = vp(r0.z, r0.w,
                (tt[4] + tt[6] + tt[12] + tt[14] - (tt[0] + tt[2] + tt[8] + tt[10])) * 0.25f,
                (tt[5] + tt[7] + tt[13] + tt[15] - (tt[1] + tt[3] + tt[9] + tt[11])) * 0.25f);
            const float vp2 = vp(r1.x, r1.y,
                (tt[2] + tt[6] + tt[10] + tt[14] - (tt[0] + tt[4] + tt[8] + tt[12])) * 0.25f,
                (tt[3] + tt[7] + tt[11] + tt[15] - (tt[1] + tt[5] + tt[9] + tt[13])) * 0.25f);
            const float vp3 = vp(r1.z, r1.w,
                (tt[0] + tt[2] + tt[4] + tt[6] - (tt[8] + tt[10] + tt[12] + tt[14])) * 0.25f,
                (tt[1] + tt[3] + tt[5] + tt[7] - (tt[9] + tt[11] + tt[13] + tt[15])) * 0.25f);
            vpS += (vp1 + vp2 + vp3) * (1.0f / 3.0f);

            const float s2[8] = {-1, -1, 1, 1, -1, -1, 1, 1};
            const float s4[8] = {-1, 1, -1, 1, -1, 1, -1, 1};
            const float s6[8] = {1, 1, 1, 1, -1, -1, -1, -1};
            float ssum = 0.f;
#pragma unroll
            for (int j = 0; j < 8; ++j) {
                const float px = r0.x + r0.z * s2[j] + r1.x * s4[j] + r1.z * s6[j];
                const float py = r0.y + r0.w * s2[j] + r1.y * s4[j] + r1.w * s6[j];
                const float tx = (tt[2 * j]     - acx) / aw;
                const float ty = (tt[2 * j + 1] - acy) / ah;
                const float dx = fabsf(px - tx);
                const float dy = fabsf(py - ty);
                ssum += (dx <= (1.0f / 9.0f)) ? 4.5f * dx * dx : dx - (0.5f / 9.0f);
                ssum += (dy <= (1.0f / 9.0f)) ? 4.5f * dy * dy : dy - (0.5f / 9.0f);
            }
            regS += ssum * (1.0f / 16.0f);
        }
    };

    epilogue(a0, an0, bn0, bd0, kb0);
    epilogue(a1, an1, bn1, bd1, kb1);

    // ---- block reduction (deterministic) ------------------------------
#pragma unroll
    for (int off = 32; off; off >>= 1) {
        clsS += __shfl_down(clsS, off);
        regS += __shfl_down(regS, off);
        vpS  += __shfl_down(vpS, off);
        posC += __shfl_down(posC, off);
    }
    __shared__ float s_red[4][4];
    const int wv = tid >> 6, ln = tid & 63;
    if (ln == 0) {
        s_red[wv][0] = clsS; s_red[wv][1] = regS;
        s_red[wv][2] = vpS;  s_red[wv][3] = posC;
    }
    __syncthreads();
    if (tid == 0) {
        float C = 0, R = 0, V = 0, P = 0;
        for (int w = 0; w < 4; ++w) {
            C += s_red[w][0]; R += s_red[w][1];
            V += s_red[w][2]; P += s_red[w][3];
        }
        float* out = partials + ((size_t)b * NBLK + blockIdx.x) * 4;
        out[0] = C; out[1] = R; out[2] = V; out[3] = P;
    }
}

// ---------------------------------------------------------------------------
// Per-image reduce + normalize. grid = B blocks.
// ---------------------------------------------------------------------------
__global__ __launch_bounds__(BLOCK) void reduce_img(
    const float* __restrict__ partials,  // (B, NBLK, 4)
    float* __restrict__ imgloss)         // (B, 3)
{
    const int b = blockIdx.x, tid = threadIdx.x;
    float c = 0.f, r = 0.f, v = 0.f, p = 0.f;
    for (int i = tid; i < NBLK; i += BLOCK) {
        const float* q = partials + ((size_t)b * NBLK + i) * 4;
        c += q[0]; r += q[1]; v += q[2]; p += q[3];
    }
#pragma unroll
    for (int off = 32; off; off >>= 1) {
        c += __shfl_down(c, off); r += __shfl_down(r, off);
        v += __shfl_down(v, off); p += __shfl_down(p, off);
    }
    __shared__ float s[4][4];
    const int wv = tid >> 6, ln = tid & 63;
    if (ln == 0) { s[wv][0] = c; s[wv][1] = r; s[wv][2] = v; s[wv][3] = p; }
    __syncthreads();
    if (tid == 0) {
        float C = 0, R = 0, V = 0, P = 0;
        for (int w = 0; w < 4; ++w) {
            C += s[w][0]; R += s[w][1]; V += s[w][2]; P += s[w][3];
        }
        const float np_ = fmaxf(P, 1.0f);
        imgloss[b * 3 + 0] = C / np_;
        imgloss[b * 3 + 1] = R / np_;
        imgloss[b * 3 + 2] = V / np_;
    }
}

__global__ void final_avg(const float* __restrict__ imgloss,
                          float* __restrict__ out)
{
    const int k = threadIdx.x;
    if (k < 3) {
        float s = 0.f;
        for (int b = 0; b < B_N; ++b) s += imgloss[b * 3 + k];
        out[k] = s * 0.125f;
    }
}

}  // namespace

extern "C" void kernel_launch(void* const* d_in, const int* in_sizes, int n_in,
                              void* d_out, int out_size, void* d_ws, size_t ws_size,
                              hipStream_t stream)
{
    const float* cls_    = (const float*)d_in[0];  // classifications (B,A,C)
    const float* reg_    = (const float*)d_in[1];  // regressions (B,A,8)
    const float* anchors = (const float*)d_in[2];  // anchors (1,A,4)
    const float* ann     = (const float*)d_in[3];  // annotations (B,M,18)
    // d_in[4] = embeddings: unused by the reference.

    float* partials = (float*)d_ws;                      // B*NBLK*4 floats
    float* imgloss  = partials + (size_t)B_N * NBLK * 4; // B*3 floats

    dim3 grid(NBLK, B_N);
    focal_main<<<grid, dim3(BLOCK), 0, stream>>>(cls_, reg_, anchors, ann, partials);
    reduce_img<<<dim3(B_N), dim3(BLOCK), 0, stream>>>(partials, imgloss);
    final_avg<<<dim3(1), dim3(64), 0, stream>>>(imgloss, (float*)d_out);
}

// Round 3
// 83.414 us; speedup vs baseline: 1.0042x; 1.0042x over previous
//
#include <hip/hip_runtime.h>
#include <hip/hip_bf16.h>

namespace {

constexpr int B_N = 8;
constexpr int A_N = 100000;
constexpr int C_N = 8;
constexpr int M_N = 128;
constexpr int BLOCK = 256;
constexpr int NBLK = (A_N + BLOCK - 1) / BLOCK;  // 391
constexpr int BSTR = 8;  // floats per box record (padded for alignment)

// ---------------------------------------------------------------------------
// Pre-kernel: derive box2d records {x1,y1,x2,y2,area} per (image, box).
// Validity folded into coordinates: invalid -> (1e30,1e30,-1e30,-1e30), area 0
// so the main loop's update condition can never fire (inter=0, bn>=0).
// ---------------------------------------------------------------------------
__global__ void prep_boxes(const float* __restrict__ ann_,  // (B, M, 18)
                           float* __restrict__ boxbuf)      // (B, M, BSTR)
{
    const int i = blockIdx.x * blockDim.x + threadIdx.x;
    if (i >= B_N * M_N) return;
    const float* t = ann_ + (size_t)i * 18;
    float minx = t[0], maxx = t[0], miny = t[1], maxy = t[1];
#pragma unroll
    for (int j = 1; j < 8; ++j) {
        const float xj = t[2 * j], yj = t[2 * j + 1];
        minx = fminf(minx, xj); maxx = fmaxf(maxx, xj);
        miny = fminf(miny, yj); maxy = fmaxf(maxy, yj);
    }
    float area = (maxx - minx) * (maxy - miny);
    if (t[17] < 0.0f) {
        minx = 1e30f; miny = 1e30f; maxx = -1e30f; maxy = -1e30f; area = 0.0f;
    }
    float* o = boxbuf + (size_t)i * BSTR;
    o[0] = minx; o[1] = miny; o[2] = maxx; o[3] = maxy;
    o[4] = area; o[5] = 0.f;  o[6] = 0.f;  o[7] = 0.f;
}

// ---------------------------------------------------------------------------
// Main kernel: 1 anchor/thread, grid (NBLK, B) = 3128 blocks (12512 waves).
// Box records read via WAVE-UNIFORM addresses -> s_load into SGPRs; each
// inner-loop VALU op uses the box value as its single SGPR operand. 16 VALU
// ops per anchor-box pair, no LDS, no per-iter address math.
// State (bn, bs) with bs = bn + bd: update condition  in*bs > bn*s  where
// s = aarea + barea; on update bs_new = s exactly (ua = s - in cancels).
// ---------------------------------------------------------------------------
__global__ __launch_bounds__(BLOCK) void focal_main(
    const float* __restrict__ cls_,      // (B, A, C)
    const float* __restrict__ reg_,      // (B, A, 8)
    const float* __restrict__ anchors_,  // (1, A, 4)
    const float* __restrict__ ann_,      // (B, M, 18)
    const float* __restrict__ boxbuf,    // (B, M, BSTR)
    float* __restrict__ partials)        // (B, NBLK, 4)
{
    const int b   = blockIdx.y;
    const int tid = threadIdx.x;
    const int a   = blockIdx.x * BLOCK + tid;
    const int ca  = min(a, A_N - 1);     // clamp for safe tail loads

    const float4 an = ((const float4*)anchors_)[ca];
    const float aarea = (an.z - an.x) * (an.w - an.y);

    const float* __restrict__ bx = boxbuf + (size_t)b * M_N * BSTR;

    float bn = 0.f, bs = 1.f;
    int   kb = 0;

#pragma unroll 16
    for (int m = 0; m < M_N; ++m) {
        const float x1 = bx[m * BSTR + 0];   // uniform -> SGPR
        const float y1 = bx[m * BSTR + 1];
        const float x2 = bx[m * BSTR + 2];
        const float y2 = bx[m * BSTR + 3];
        const float ba = bx[m * BSTR + 4];
        const float iw = fminf(an.z, x2) - fmaxf(an.x, x1);
        const float ih = fminf(an.w, y2) - fmaxf(an.y, y1);
        const float in_ = fmaxf(iw, 0.f) * fmaxf(ih, 0.f);
        const float s   = aarea + ba;
        const bool  u   = in_ * bs > bn * s;   // iou_m > iou_best, first-wins
        bn = u ? in_ : bn;
        bs = u ? s   : bs;
        kb = u ? m   : kb;
    }
    const float bd = bs - bn;                  // union area of best

    float clsS = 0.f, regS = 0.f, vpS = 0.f, posC = 0.f;

    if (a < A_N) {
        const bool pos = (bn + bn) >= bd;          // iou >= 0.5
        const bool neg = (5.0f * bn) < (bd + bd);  // iou < 0.4

        // ---- classification focal loss --------------------------------
        const float* cp = cls_ + ((size_t)b * A_N + a) * C_N;
        const float4 cA = ((const float4*)cp)[0];
        const float4 cB = ((const float4*)cp)[1];
        const float pv[8] = {cA.x, cA.y, cA.z, cA.w, cB.x, cB.y, cB.z, cB.w};

        const float* annb = ann_ + (size_t)b * M_N * 18;
        float tt[16];
        int   kc = -1;
        if (pos) {  // rare: gather assigned annotation from global
            const float* t = annb + kb * 18;
#pragma unroll
            for (int j = 0; j < 16; ++j) tt[j] = t[j];
            kc = (int)t[17];
        }

        float sneg = 0.f, pkc = 0.5f, negkc = 0.f;
#pragma unroll
        for (int c = 0; c < C_N; ++c) {
            const float pc   = fminf(fmaxf(pv[c], 1e-4f), 1.0f - 1e-4f);
            const float term = 0.75f * pc * pc * (-__logf(1.0f - pc));
            sneg += term;
            if (c == kc) { pkc = pc; negkc = term; }  // static unrolled selects
        }
        if (pos | neg)
            clsS = pos ? (sneg - negkc +
                          0.25f * (1.0f - pkc) * (1.0f - pkc) * (-__logf(pkc)))
                       : sneg;

        // ---- regression + vp (pos anchors only) -----------------------
        if (pos) {
            posC = 1.0f;
            const float aw  = an.z - an.x;
            const float ah  = an.w - an.y;
            const float acx = an.x + 0.5f * aw;
            const float acy = an.y + 0.5f * ah;

            const float* rp = reg_ + ((size_t)b * A_N + a) * 8;
            const float4 r0 = ((const float4*)rp)[0];
            const float4 r1 = ((const float4*)rp)[1];

            auto vp = [](float rx, float ry, float tx, float ty) {
                const float denom = sqrtf(rx * rx + ry * ry) * sqrtf(tx * tx + ty * ty);
                return 1.0f - (rx * tx + ry * ty) / fmaxf(denom, 1e-8f);
            };
            const float vp1 = vp(r0.z, r0.w,
                (tt[4] + tt[6] + tt[12] + tt[14] - (tt[0] + tt[2] + tt[8] + tt[10])) * 0.25f,
                (tt[5] + tt[7] + tt[13] + tt[15] - (tt[1] + tt[3] + tt[9] + tt[11])) * 0.25f);
            const float vp2 = vp(r1.x, r1.y,
                (tt[2] + tt[6] + tt[10] + tt[14] - (tt[0] + tt[4] + tt[8] + tt[12])) * 0.25f,
                (tt[3] + tt[7] + tt[11] + tt[15] - (tt[1] + tt[5] + tt[9] + tt[13])) * 0.25f);
            const float vp3 = vp(r1.z, r1.w,
                (tt[0] + tt[2] + tt[4] + tt[6] - (tt[8] + tt[10] + tt[12] + tt[14])) * 0.25f,
                (tt[1] + tt[3] + tt[5] + tt[7] - (tt[9] + tt[11] + tt[13] + tt[15])) * 0.25f);
            vpS = (vp1 + vp2 + vp3) * (1.0f / 3.0f);

            const float s2[8] = {-1, -1, 1, 1, -1, -1, 1, 1};
            const float s4[8] = {-1, 1, -1, 1, -1, 1, -1, 1};
            const float s6[8] = {1, 1, 1, 1, -1, -1, -1, -1};
            float ssum = 0.f;
#pragma unroll
            for (int j = 0; j < 8; ++j) {
                const float px = r0.x + r0.z * s2[j] + r1.x * s4[j] + r1.z * s6[j];
                const float py = r0.y + r0.w * s2[j] + r1.y * s4[j] + r1.w * s6[j];
                const float tx = (tt[2 * j]     - acx) / aw;
                const float ty = (tt[2 * j + 1] - acy) / ah;
                const float dx = fabsf(px - tx);
                const float dy = fabsf(py - ty);
                ssum += (dx <= (1.0f / 9.0f)) ? 4.5f * dx * dx : dx - (0.5f / 9.0f);
                ssum += (dy <= (1.0f / 9.0f)) ? 4.5f * dy * dy : dy - (0.5f / 9.0f);
            }
            regS = ssum * (1.0f / 16.0f);
        }
    }

    // ---- block reduction (deterministic) ------------------------------
#pragma unroll
    for (int off = 32; off; off >>= 1) {
        clsS += __shfl_down(clsS, off);
        regS += __shfl_down(regS, off);
        vpS  += __shfl_down(vpS, off);
        posC += __shfl_down(posC, off);
    }
    __shared__ float s_red[4][4];
    const int wv = tid >> 6, ln = tid & 63;
    if (ln == 0) {
        s_red[wv][0] = clsS; s_red[wv][1] = regS;
        s_red[wv][2] = vpS;  s_red[wv][3] = posC;
    }
    __syncthreads();
    if (tid == 0) {
        float C = 0, R = 0, V = 0, P = 0;
        for (int w = 0; w < 4; ++w) {
            C += s_red[w][0]; R += s_red[w][1];
            V += s_red[w][2]; P += s_red[w][3];
        }
        float* out = partials + ((size_t)b * NBLK + blockIdx.x) * 4;
        out[0] = C; out[1] = R; out[2] = V; out[3] = P;
    }
}

// ---------------------------------------------------------------------------
// Single reduction kernel: per-image sum + num_pos normalize + batch average.
// One block, 256 threads; loops over the 8 images sequentially.
// ---------------------------------------------------------------------------
__global__ __launch_bounds__(BLOCK) void reduce_all(
    const float* __restrict__ partials,  // (B, NBLK, 4)
    float* __restrict__ out)             // (3,)
{
    const int tid = threadIdx.x;
    __shared__ float s[4][4];
    __shared__ float accum[3];
    if (tid == 0) { accum[0] = 0.f; accum[1] = 0.f; accum[2] = 0.f; }

    for (int b = 0; b < B_N; ++b) {
        float c = 0.f, r = 0.f, v = 0.f, p = 0.f;
        for (int i = tid; i < NBLK; i += BLOCK) {
            const float* q = partials + ((size_t)b * NBLK + i) * 4;
            c += q[0]; r += q[1]; v += q[2]; p += q[3];
        }
#pragma unroll
        for (int off = 32; off; off >>= 1) {
            c += __shfl_down(c, off); r += __shfl_down(r, off);
            v += __shfl_down(v, off); p += __shfl_down(p, off);
        }
        const int wv = tid >> 6, ln = tid & 63;
        if (ln == 0) { s[wv][0] = c; s[wv][1] = r; s[wv][2] = v; s[wv][3] = p; }
        __syncthreads();
        if (tid == 0) {
            float C = 0, R = 0, V = 0, P = 0;
            for (int w = 0; w < 4; ++w) {
                C += s[w][0]; R += s[w][1]; V += s[w][2]; P += s[w][3];
            }
            const float np_ = fmaxf(P, 1.0f);
            accum[0] += C / np_; accum[1] += R / np_; accum[2] += V / np_;
        }
        __syncthreads();
    }
    if (tid == 0) {
        out[0] = accum[0] * 0.125f;
        out[1] = accum[1] * 0.125f;
        out[2] = accum[2] * 0.125f;
    }
}

}  // namespace

extern "C" void kernel_launch(void* const* d_in, const int* in_sizes, int n_in,
                              void* d_out, int out_size, void* d_ws, size_t ws_size,
                              hipStream_t stream)
{
    const float* cls_    = (const float*)d_in[0];  // classifications (B,A,C)
    const float* reg_    = (const float*)d_in[1];  // regressions (B,A,8)
    const float* anchors = (const float*)d_in[2];  // anchors (1,A,4)
    const float* ann     = (const float*)d_in[3];  // annotations (B,M,18)
    // d_in[4] = embeddings: unused by the reference.

    float* boxbuf   = (float*)d_ws;                          // B*M*BSTR floats
    float* partials = boxbuf + (size_t)B_N * M_N * BSTR;     // B*NBLK*4 floats

    prep_boxes<<<dim3((B_N * M_N + BLOCK - 1) / BLOCK), dim3(BLOCK), 0, stream>>>(ann, boxbuf);
    focal_main<<<dim3(NBLK, B_N), dim3(BLOCK), 0, stream>>>(cls_, reg_, anchors, ann,
                                                            boxbuf, partials);
    reduce_all<<<dim3(1), dim3(BLOCK), 0, stream>>>(partials, (float*)d_out);
}